// Round 3
// baseline (427.090 us; speedup 1.0000x reference)
//
#include <hip/hip_runtime.h>
#include <math.h>

#define F_DIM 4096
#define BATCH 16384

// Robust scalar decode: Python scalar 7 may be stored as int32/int64/fp32.
__device__ __forceinline__ int decode_nb(const void* p) {
    int i = *(const int*)p;                 // int32 / low word of int64
    if (i >= 0 && i < 1000) return i;
    float f = *(const float*)p;             // fp32 encoding
    if (f >= 0.0f && f < 1000.0f && f == floorf(f)) return (int)f;
    return 0;
}

// out[r, j] = x[r, j] * w[j] + b[nb, j]   — all fp32, elementwise.
// One thread handles one float4 (16 B per tensor access).
__global__ __launch_bounds__(256) void ShareLinear_kernel(
    const float4* __restrict__ x,
    const float4* __restrict__ w,
    const float*  __restrict__ b,
    const void*   __restrict__ nb,
    float4* __restrict__ out)
{
    constexpr int GROUPS_PER_ROW = F_DIM / 4;            // 1024 (power of two)
    const size_t gid = (size_t)blockIdx.x * blockDim.x + threadIdx.x;
    const int col = (int)(gid & (GROUPS_PER_ROW - 1));   // float4 group within row

    const int nbi = decode_nb(nb);

    const float4* bv = (const float4*)(b + (size_t)nbi * F_DIM);

    float4 xq = x[gid];
    float4 wq = w[col];    // 16 KiB total: L1/L2-resident
    float4 bq = bv[col];   // 16 KiB row: L1/L2-resident

    float4 r;
    r.x = fmaf(xq.x, wq.x, bq.x);
    r.y = fmaf(xq.y, wq.y, bq.y);
    r.z = fmaf(xq.z, wq.z, bq.z);
    r.w = fmaf(xq.w, wq.w, bq.w);

    out[gid] = r;
}

extern "C" void kernel_launch(void* const* d_in, const int* in_sizes, int n_in,
                              void* d_out, int out_size, void* d_ws, size_t ws_size,
                              hipStream_t stream) {
    const float4* x = (const float4*)d_in[0];   // fp32 input  (16384 x 4096)
    const float4* w = (const float4*)d_in[1];   // fp32 weight (4096)
    const float*  b = (const float*)d_in[2];    // fp32 bias   (1000 x 4096)
    const void*  nb = d_in[3];                  // scalar

    float4* out = (float4*)d_out;               // fp32 output

    const size_t ngroups = (size_t)BATCH * F_DIM / 4;   // 16,777,216
    const int block = 256;
    const int grid = (int)((ngroups + block - 1) / block);  // 65536 blocks

    ShareLinear_kernel<<<grid, block, 0, stream>>>(x, w, b, nb, out);
}